// Round 11
// baseline (263.342 us; speedup 1.0000x reference)
//
#include <hip/hip_runtime.h>

#define N_NODES 250000
#define N_EDGES 4000000
#define HID 32
#define NN 50
#define NF 3
#define OUT_COLS (NN + NF)   // 53

#define NB 1024                                   // nodes per bucket
#define NBKT ((N_NODES + NB - 1) / NB)            // 245 buckets
#define CHUNK 8192                                // edges per partition block
#define NPBLK ((N_EDGES + CHUNK - 1) / CHUNK)     // 489
#define BCAP_SLOT 17152                           // fixed bucket capacity (mean+6sigma)

typedef float float2v __attribute__((ext_vector_type(2)));

__device__ __forceinline__ float softplus_f(float v) {
    return fmaxf(v, 0.0f) + log1pf(expf(-fabsf(v)));
}

__device__ __forceinline__ float2v pk_fma(float a, float2v b, float2v c) {
    float2v av = {a, a};
    return __builtin_elementwise_fma(av, b, c);
}

// ---- P1: partition edges into fixed-capacity bucket regions ----
// record: w0 = col | (lrow<<18)  (col<2^18, lrow<2^10), w1 = attr bits
__global__ __launch_bounds__(512) void part_kernel(
    const int* __restrict__ ei, const float* __restrict__ ea,
    int* __restrict__ gcursor, int2* __restrict__ bpay)
{
    __shared__ int hist[NBKT];
    __shared__ int excl[NBKT];
    __shared__ int gbase[NBKT];
    __shared__ int asn[NBKT];
    __shared__ int sh[512];
    __shared__ int idx[CHUNK];       // e | (lrow<<22)   (e < 2^22)
    __shared__ unsigned char bkt[CHUNK];

    int t = threadIdx.x;
    int cbb = blockIdx.x * CHUNK;
    int cnt = N_EDGES - cbb; if (cnt > CHUNK) cnt = CHUNK;

    for (int i = t; i < NBKT; i += 512) hist[i] = 0;
    __syncthreads();

    // pass 1: load rows ONCE into registers, count per bucket
    int r[CHUNK / 512];
    #pragma unroll
    for (int j = 0; j < CHUNK / 512; j++) {
        int o = j * 512 + t;
        r[j] = (o < cnt) ? ei[cbb + o] : -1;
        if (o < cnt) atomicAdd(&hist[r[j] >> 10], 1);
    }
    __syncthreads();

    // scan 245 counters (Hillis-Steele over first 256 slots)
    int v = (t < NBKT) ? hist[t] : 0;
    sh[t] = v;
    __syncthreads();
    #pragma unroll
    for (int off = 1; off < 256; off <<= 1) {
        int a = (t >= off && t < 256) ? sh[t - off] : 0;
        __syncthreads();
        if (t < 256) sh[t] += a;
        __syncthreads();
    }
    if (t < NBKT) {
        int ex = sh[t] - v;
        excl[t] = ex;
        asn[t] = ex;
        int base = 0;
        if (v > 0) base = atomicAdd(&gcursor[t], v);
        gbase[t] = t * BCAP_SLOT + base;
    }
    __syncthreads();

    // pass 2: LDS reorder (bucket-major slots) — rows from registers
    #pragma unroll
    for (int j = 0; j < CHUNK / 512; j++) {
        int o = j * 512 + t;
        if (o < cnt) {
            int row = r[j];
            int b = row >> 10;
            int lrow = row & (NB - 1);
            int slot = atomicAdd(&asn[b], 1);
            idx[slot] = (cbb + o) | (lrow << 22);
            bkt[slot] = (unsigned char)b;
        }
    }
    __syncthreads();

    // pass 3: emit bucket-contiguous runs
    for (int s = t; s < cnt; s += 512) {
        int packed = idx[s];
        int e = packed & 0x3FFFFF;
        int lrow = ((unsigned)packed) >> 22;
        int b = bkt[s];
        int gpos = gbase[b] + (s - excl[b]);
        if (gpos < (b + 1) * BCAP_SLOT) {    // overflow clamp (never in practice)
            int2 rec;
            rec.x = (ei[N_EDGES + e]) | (lrow << 18);
            rec.y = __float_as_int(ea[e]);
            bpay[gpos] = rec;
        }
    }
}

// ---- P2: per-bucket counting sort into CSR order (in-place via LDS) ----
__global__ __launch_bounds__(512) void csr_kernel(
    int2* __restrict__ bpay, const int* __restrict__ gcursor,
    int* __restrict__ offs, int* __restrict__ counts)
{
    __shared__ int2 recs[BCAP_SLOT]; // 137,216 B
    __shared__ int hist[NB];         // 4 KB
    __shared__ int excl[NB];         // 4 KB
    __shared__ int sh[512];          // 2 KB

    int b = blockIdx.x;
    int t = threadIdx.x;
    int nb0 = b << 10;
    int beg = b * BCAP_SLOT;
    int cnt = gcursor[b];
    if (cnt > BCAP_SLOT) cnt = BCAP_SLOT;

    for (int i = t; i < NB; i += 512) hist[i] = 0;
    __syncthreads();

    for (int s = t; s < cnt; s += 512) {
        int2 rec = bpay[beg + s];
        atomicAdd(&hist[(rec.x >> 18) & (NB - 1)], 1);
    }
    __syncthreads();

    int a0 = hist[2 * t], a1 = hist[2 * t + 1];
    int ps = a0 + a1;
    sh[t] = ps;
    __syncthreads();
    #pragma unroll
    for (int off = 1; off < 512; off <<= 1) {
        int a = (t >= off) ? sh[t - off] : 0;
        __syncthreads();
        sh[t] += a;
        __syncthreads();
    }
    int pairExcl = sh[t] - ps;
    excl[2 * t] = pairExcl;
    excl[2 * t + 1] = pairExcl + a0;
    __syncthreads();

    for (int i = t; i < NB; i += 512) {
        int n = nb0 + i;
        if (n < N_NODES) {
            offs[n] = beg + excl[i];
            counts[n] = hist[i];
        }
    }

    for (int s = t; s < cnt; s += 512) {
        int2 rec = bpay[beg + s];
        int lrow = (rec.x >> 18) & (NB - 1);
        int pos = atomicAdd(&excl[lrow], 1);
        recs[pos] = rec;
    }
    __syncthreads();

    for (int s = t; s < cnt; s += 512) bpay[beg + s] = recs[s];
}

// ---- P3: gather — layer-1 only (W2 hoisted), row-terms hoisted,
//      2 contiguous slices/node, unmasked full chunks + guarded tail ----
__global__ __launch_bounds__(256) void gather_kernel(
    const float* __restrict__ x, const int* __restrict__ offs,
    const int* __restrict__ counts, const int2* __restrict__ sorted,
    const float* __restrict__ W1, const float* __restrict__ b1,
    const float* __restrict__ W2, const float* __restrict__ b2,
    const float* __restrict__ Wc, const float* __restrict__ bc,
    const float* __restrict__ Wmu, const float* __restrict__ bmu,
    const float* __restrict__ Wsig, const float* __restrict__ bsig,
    const float* __restrict__ high,
    float* __restrict__ sum_out, float* __restrict__ out)
{
    int t = blockIdx.x * 256 + threadIdx.x;
    int n = t >> 1;
    int slice = t & 1;
    bool valid = n < N_NODES;
    int nn = valid ? n : 0;

    int beg = offs[nn];
    int deg = valid ? counts[nn] : 0;
    int half = (deg + 1) >> 1;
    int myCnt = slice ? (deg - half) : half;
    int s0 = beg + slice * half;

    float4 xr = *(const float4*)(x + 4 * (size_t)nn);

    const float2v* W1v = (const float2v*)W1;   // [9][16]
    const float2v* b1v = (const float2v*)b1;

    // hoist row-terms: arow = b1 + xr @ W1[0:4]  (edge-invariant)
    float2v arow[16];
    #pragma unroll
    for (int k2 = 0; k2 < 16; k2++) {
        float2v a = b1v[k2];
        a = pk_fma(xr.x, W1v[0 * 16 + k2], a);
        a = pk_fma(xr.y, W1v[1 * 16 + k2], a);
        a = pk_fma(xr.z, W1v[2 * 16 + k2], a);
        a = pk_fma(xr.w, W1v[3 * 16 + k2], a);
        arow[k2] = a;
    }

    // S = sum over edges of relu(in @ W1 + b1)
    float2v acc2[16];
    #pragma unroll
    for (int j2 = 0; j2 < 16; j2++) { float2v z = {0.f, 0.f}; acc2[j2] = z; }

    int nFull = myCnt & ~3;          // edges handled in unmasked 4-chunks

    if (nFull > 0) {
        // prologue: chunk 0 (fully in-bounds, no masks)
        float ev0[4];
        float4 xc0[4];
        {
            int4 ra = *(const int4*)(sorted + s0);
            int4 rb = *(const int4*)(sorted + s0 + 2);
            int rx[4] = {ra.x, ra.z, rb.x, rb.z};
            int ry[4] = {ra.y, ra.w, rb.y, rb.w};
            #pragma unroll
            for (int j = 0; j < 4; j++) {
                ev0[j] = __int_as_float(ry[j]);
                xc0[j] = *(const float4*)(x + 4 * (size_t)(rx[j] & 0x3FFFF));
            }
        }

        for (int c = 0; c < nFull; c += 4) {
            // prefetch next chunk; clamp address so loads stay in-bounds
            int c1 = c + 4;
            int cl = (c1 < nFull) ? c1 : c;
            int4 ra = *(const int4*)(sorted + s0 + cl);
            int4 rb = *(const int4*)(sorted + s0 + cl + 2);
            int rx[4] = {ra.x, ra.z, rb.x, rb.z};
            int ry[4] = {ra.y, ra.w, rb.y, rb.w};
            float ev1[4];
            float4 xc1[4];
            #pragma unroll
            for (int j = 0; j < 4; j++) {
                ev1[j] = __int_as_float(ry[j]);
                xc1[j] = *(const float4*)(x + 4 * (size_t)(rx[j] & 0x3FFFF));
            }

            // layer-1 column-terms; relu + accumulate (no masks)
            #pragma unroll
            for (int k2 = 0; k2 < 16; k2++) {
                float2v w4 = W1v[4 * 16 + k2];
                float2v w5 = W1v[5 * 16 + k2];
                float2v w6 = W1v[6 * 16 + k2];
                float2v w7 = W1v[7 * 16 + k2];
                float2v w8 = W1v[8 * 16 + k2];
                #pragma unroll
                for (int j = 0; j < 4; j++) {
                    float2v a = arow[k2];
                    a = pk_fma(xc0[j].x, w4, a);
                    a = pk_fma(xc0[j].y, w5, a);
                    a = pk_fma(xc0[j].z, w6, a);
                    a = pk_fma(xc0[j].w, w7, a);
                    a = pk_fma(ev0[j],   w8, a);
                    float2v zero = {0.0f, 0.0f};
                    a = __builtin_elementwise_max(a, zero);
                    acc2[k2] = acc2[k2] + a;
                }
            }

            #pragma unroll
            for (int j = 0; j < 4; j++) { ev0[j] = ev1[j]; xc0[j] = xc1[j]; }
        }
    }

    // tail: up to 3 edges, guarded scalar loop
    for (int p = nFull; p < myCnt; ++p) {
        int2 ce = sorted[s0 + p];
        float ev = __int_as_float(ce.y);
        float4 xc = *(const float4*)(x + 4 * (size_t)(ce.x & 0x3FFFF));
        #pragma unroll
        for (int k2 = 0; k2 < 16; k2++) {
            float2v a = arow[k2];
            a = pk_fma(xc.x, W1v[4 * 16 + k2], a);
            a = pk_fma(xc.y, W1v[5 * 16 + k2], a);
            a = pk_fma(xc.z, W1v[6 * 16 + k2], a);
            a = pk_fma(xc.w, W1v[7 * 16 + k2], a);
            a = pk_fma(ev,   W1v[8 * 16 + k2], a);
            float2v zero = {0.0f, 0.0f};
            a = __builtin_elementwise_max(a, zero);
            acc2[k2] = acc2[k2] + a;
        }
    }

    // combine the 2 slices (lanes 2k, 2k+1)
    float* accf = (float*)acc2;
    #pragma unroll
    for (int j = 0; j < 32; j++) accf[j] += __shfl_xor(accf[j], 1, 64);

    float c_val = 0.0f;
    if (valid && slice == 0) {
        // epilogue: agg = S @ W2 + deg*b2  (hoisted layer 2)
        float fdeg = (float)deg;
        float aout[32];
        #pragma unroll
        for (int j = 0; j < 32; j++) aout[j] = fdeg * b2[j];
        for (int k = 0; k < 32; k++) {
            float sk = accf[k];
            #pragma unroll
            for (int j = 0; j < 32; j++) aout[j] = fmaf(sk, W2[k * 32 + j], aout[j]);
        }

        float zc = bc[0];
        zc = fmaf(xr.x, Wc[0], zc);
        zc = fmaf(xr.y, Wc[1], zc);
        zc = fmaf(xr.z, Wc[2], zc);
        zc = fmaf(xr.w, Wc[3], zc);
        #pragma unroll
        for (int j = 0; j < 32; j++) zc = fmaf(aout[j], Wc[4 + j], zc);
        c_val = softplus_f(zc + 1e-10f);

        int g = n / NN;
        int i = n - g * NN;
        out[(size_t)g * OUT_COLS + i] = c_val;   // unnormalized; div rescales

        if (i >= NN - NF) {
            float zm = bmu[0], zs = bsig[0];
            zm = fmaf(xr.x, Wmu[0], zm);   zs = fmaf(xr.x, Wsig[0], zs);
            zm = fmaf(xr.y, Wmu[1], zm);   zs = fmaf(xr.y, Wsig[1], zs);
            zm = fmaf(xr.z, Wmu[2], zm);   zs = fmaf(xr.z, Wsig[2], zs);
            zm = fmaf(xr.w, Wmu[3], zm);   zs = fmaf(xr.w, Wsig[3], zs);
            #pragma unroll
            for (int j = 0; j < 32; j++) {
                zm = fmaf(aout[j], Wmu[4 + j], zm);
                zs = fmaf(aout[j], Wsig[4 + j], zs);
            }
            float alpha = softplus_f(zm + 1e-20f) + 1e-20f;
            float beta  = softplus_f(zs + 1e-20f) + 1e-20f;
            int k = i - (NN - NF);
            out[(size_t)g * OUT_COLS + NN + k] = alpha / (alpha + beta) * high[k];
        }
    }

    __shared__ float wave_sums[4];
    float s = c_val;
    #pragma unroll
    for (int off = 32; off > 0; off >>= 1) s += __shfl_down(s, off, 64);
    int lane = threadIdx.x & 63;
    int wid  = threadIdx.x >> 6;
    if (lane == 0) wave_sums[wid] = s;
    __syncthreads();
    if (threadIdx.x == 0) {
        float tt = wave_sums[0] + wave_sums[1] + wave_sums[2] + wave_sums[3];
        atomicAdd(sum_out, tt);
    }
}

// ---- P4: in-place normalization of inventory columns ----
__global__ __launch_bounds__(256) void div_kernel(
    const float* __restrict__ sum_in, float* __restrict__ out)
{
    int n = blockIdx.x * 256 + threadIdx.x;
    if (n >= N_NODES) return;
    float inv = 1.0f / (*sum_in + 1e-20f);
    int g = n / NN;
    int i = n - g * NN;
    out[(size_t)g * OUT_COLS + i] *= inv;
}

extern "C" void kernel_launch(void* const* d_in, const int* in_sizes, int n_in,
                              void* d_out, int out_size, void* d_ws, size_t ws_size,
                              hipStream_t stream)
{
    const float* x    = (const float*)d_in[0];
    const int*   ei   = (const int*)d_in[1];
    const float* ea   = (const float*)d_in[2];
    const float* high = (const float*)d_in[3];
    const float* W1   = (const float*)d_in[4];
    const float* b1   = (const float*)d_in[5];
    const float* W2   = (const float*)d_in[6];
    const float* b2   = (const float*)d_in[7];
    const float* Wc   = (const float*)d_in[8];
    const float* bc   = (const float*)d_in[9];
    const float* Wmu  = (const float*)d_in[10];
    const float* bmu  = (const float*)d_in[11];
    const float* Wsig = (const float*)d_in[12];
    const float* bsig = (const float*)d_in[13];
    float* out = (float*)d_out;

    char* ws = (char*)d_ws;
    int2*  bpay    = (int2*)ws;                    // 245*17152*8 = 33,617,920 B
    int*   gcursor = (int*)(ws + 33617920);        // 1024 B
    int*   offs    = (int*)(ws + 33618944);        // 1,000,000 B
    int*   counts  = (int*)(ws + 34618944);        // 1,000,000 B
    float* ssum    = (float*)(ws + 35618944);      // 4 B

    hipMemsetAsync(gcursor, 0, 1024, stream);
    hipMemsetAsync(ssum, 0, 4, stream);

    part_kernel<<<NPBLK, 512, 0, stream>>>(ei, ea, gcursor, bpay);
    csr_kernel<<<NBKT, 512, 0, stream>>>(bpay, gcursor, offs, counts);
    gather_kernel<<<(N_NODES * 2 + 255) / 256, 256, 0, stream>>>(
        x, offs, counts, bpay, W1, b1, W2, b2, Wc, bc, Wmu, bmu, Wsig, bsig,
        high, ssum, out);
    div_kernel<<<(N_NODES + 255) / 256, 256, 0, stream>>>(ssum, out);
}

// Round 12
// 249.653 us; speedup vs baseline: 1.0548x; 1.0548x over previous
//
#include <hip/hip_runtime.h>

#define N_NODES 250000
#define N_EDGES 4000000
#define HID 32
#define NN 50
#define NF 3
#define OUT_COLS (NN + NF)   // 53

#define NB 1024                                   // nodes per bucket
#define NBKT ((N_NODES + NB - 1) / NB)            // 245 buckets
#define CHUNK 8192                                // edges per partition block
#define NPBLK ((N_EDGES + CHUNK - 1) / CHUNK)     // 489
#define BCAP_SLOT 17152                           // fixed bucket capacity (mean+6sigma)

typedef float float2v __attribute__((ext_vector_type(2)));

__device__ __forceinline__ float softplus_f(float v) {
    return fmaxf(v, 0.0f) + log1pf(expf(-fabsf(v)));
}

__device__ __forceinline__ float2v pk_fma(float a, float2v b, float2v c) {
    float2v av = {a, a};
    return __builtin_elementwise_fma(av, b, c);
}

// ---- P1: partition edges into fixed-capacity bucket regions ----
// record: w0 = col | (lrow<<18)  (col<2^18, lrow<2^10), w1 = attr bits
// v2: ALL global reads coalesced; records staged in LDS.
__global__ __launch_bounds__(512) void part_kernel(
    const int* __restrict__ ei, const float* __restrict__ ea,
    int* __restrict__ gcursor, int2* __restrict__ bpay)
{
    __shared__ int hist[NBKT];
    __shared__ int excl[NBKT];
    __shared__ int gbase[NBKT];
    __shared__ int asn[NBKT];
    __shared__ int sh[512];
    __shared__ int2 srec[CHUNK];     // 64 KB — full records, bucket-major slots
    __shared__ unsigned char bkt[CHUNK];

    int t = threadIdx.x;
    int cbb = blockIdx.x * CHUNK;
    int cnt = N_EDGES - cbb; if (cnt > CHUNK) cnt = CHUNK;

    for (int i = t; i < NBKT; i += 512) hist[i] = 0;
    __syncthreads();

    // pass 1: coalesced row loads -> registers, count per bucket
    int r[CHUNK / 512];
    #pragma unroll
    for (int j = 0; j < CHUNK / 512; j++) {
        int o = j * 512 + t;
        r[j] = (o < cnt) ? ei[cbb + o] : -1;
        if (o < cnt) atomicAdd(&hist[r[j] >> 10], 1);
    }
    __syncthreads();

    // scan 245 counters (Hillis-Steele over first 256 slots)
    int v = (t < NBKT) ? hist[t] : 0;
    sh[t] = v;
    __syncthreads();
    #pragma unroll
    for (int off = 1; off < 256; off <<= 1) {
        int a = (t >= off && t < 256) ? sh[t - off] : 0;
        __syncthreads();
        if (t < 256) sh[t] += a;
        __syncthreads();
    }
    if (t < NBKT) {
        int ex = sh[t] - v;
        excl[t] = ex;
        asn[t] = ex;
        int base = 0;
        if (v > 0) base = atomicAdd(&gcursor[t], v);
        gbase[t] = t * BCAP_SLOT + base;
    }
    __syncthreads();

    // pass 2: coalesced col/attr loads; build records into bucket-major LDS slots
    #pragma unroll
    for (int j = 0; j < CHUNK / 512; j++) {
        int o = j * 512 + t;
        if (o < cnt) {
            int row = r[j];
            int b = row >> 10;
            int lrow = row & (NB - 1);
            int col  = ei[N_EDGES + cbb + o];   // coalesced
            float at = ea[cbb + o];             // coalesced
            int slot = atomicAdd(&asn[b], 1);
            srec[slot] = make_int2(col | (lrow << 18), __float_as_int(at));
            bkt[slot] = (unsigned char)b;
        }
    }
    __syncthreads();

    // pass 3: emit bucket-contiguous runs (sequential LDS read, coalesced write)
    for (int s = t; s < cnt; s += 512) {
        int2 rec = srec[s];
        int b = bkt[s];
        int gpos = gbase[b] + (s - excl[b]);
        if (gpos < (b + 1) * BCAP_SLOT)        // overflow clamp (never in practice)
            bpay[gpos] = rec;
    }
}

// ---- P2: per-bucket counting sort into CSR order ----
// v2: single coalesced global read into LDS; sort from LDS; scattered
// global write confined to the 137 KB bucket window (L2-absorbed).
__global__ __launch_bounds__(512) void csr_kernel(
    int2* __restrict__ bpay, const int* __restrict__ gcursor,
    int* __restrict__ offs, int* __restrict__ counts)
{
    __shared__ int2 recs[BCAP_SLOT]; // 137,216 B — unsorted records
    __shared__ int hist[NB];         // 4 KB
    __shared__ int excl[NB];         // 4 KB
    __shared__ int sh[512];          // 2 KB

    int b = blockIdx.x;
    int t = threadIdx.x;
    int nb0 = b << 10;
    int beg = b * BCAP_SLOT;
    int cnt = gcursor[b];
    if (cnt > BCAP_SLOT) cnt = BCAP_SLOT;

    for (int i = t; i < NB; i += 512) hist[i] = 0;
    // load bucket region once (coalesced); no dependency on hist yet
    for (int s = t; s < cnt; s += 512) recs[s] = bpay[beg + s];
    __syncthreads();

    // histogram from LDS
    for (int s = t; s < cnt; s += 512)
        atomicAdd(&hist[(recs[s].x >> 18) & (NB - 1)], 1);
    __syncthreads();

    // pair + Hillis-Steele scan of 1024 counters with 512 threads
    int a0 = hist[2 * t], a1 = hist[2 * t + 1];
    int ps = a0 + a1;
    sh[t] = ps;
    __syncthreads();
    #pragma unroll
    for (int off = 1; off < 512; off <<= 1) {
        int a = (t >= off) ? sh[t - off] : 0;
        __syncthreads();
        sh[t] += a;
        __syncthreads();
    }
    int pairExcl = sh[t] - ps;
    excl[2 * t] = pairExcl;
    excl[2 * t + 1] = pairExcl + a0;
    __syncthreads();

    // write per-node offs/counts (reads excl BEFORE it is mutated below)
    for (int i = t; i < NB; i += 512) {
        int n = nb0 + i;
        if (n < N_NODES) {
            offs[n] = beg + excl[i];
            counts[n] = hist[i];
        }
    }
    __syncthreads();   // REQUIRED: placement below mutates excl via atomicAdd

    // placement: LDS read, scattered global write within 137 KB window
    for (int s = t; s < cnt; s += 512) {
        int2 rec = recs[s];
        int lrow = (rec.x >> 18) & (NB - 1);
        int pos = atomicAdd(&excl[lrow], 1);
        bpay[beg + pos] = rec;
    }
}

// ---- P3: gather — layer-1 only (W2 hoisted), row-terms hoisted,
//      2 contiguous slices/node, masked 4-edge chunks, SW pipeline (R9) ----
__global__ __launch_bounds__(256) void gather_kernel(
    const float* __restrict__ x, const int* __restrict__ offs,
    const int* __restrict__ counts, const int2* __restrict__ sorted,
    const float* __restrict__ W1, const float* __restrict__ b1,
    const float* __restrict__ W2, const float* __restrict__ b2,
    const float* __restrict__ Wc, const float* __restrict__ bc,
    const float* __restrict__ Wmu, const float* __restrict__ bmu,
    const float* __restrict__ Wsig, const float* __restrict__ bsig,
    const float* __restrict__ high,
    float* __restrict__ sum_out, float* __restrict__ out)
{
    int t = blockIdx.x * 256 + threadIdx.x;
    int n = t >> 1;
    int slice = t & 1;
    bool valid = n < N_NODES;
    int nn = valid ? n : 0;

    int beg = offs[nn];
    int deg = valid ? counts[nn] : 0;
    int half = (deg + 1) >> 1;
    int myCnt = slice ? (deg - half) : half;
    int s0 = beg + slice * half;

    float4 xr = *(const float4*)(x + 4 * (size_t)nn);

    const float2v* W1v = (const float2v*)W1;   // [9][16]
    const float2v* b1v = (const float2v*)b1;

    // hoist row-terms: arow = b1 + xr @ W1[0:4]  (edge-invariant)
    float2v arow[16];
    #pragma unroll
    for (int k2 = 0; k2 < 16; k2++) {
        float2v a = b1v[k2];
        a = pk_fma(xr.x, W1v[0 * 16 + k2], a);
        a = pk_fma(xr.y, W1v[1 * 16 + k2], a);
        a = pk_fma(xr.z, W1v[2 * 16 + k2], a);
        a = pk_fma(xr.w, W1v[3 * 16 + k2], a);
        arow[k2] = a;
    }

    // S = sum over edges of relu(in @ W1 + b1)
    float2v acc2[16];
    #pragma unroll
    for (int j2 = 0; j2 < 16; j2++) { float2v z = {0.f, 0.f}; acc2[j2] = z; }

    // --- software pipeline: recs + xc one chunk ahead ---
    float mk0[4], ev0[4];
    float4 xc0[4];
    {
        int4 ra = make_int4(0, 0, 0, 0), rb = ra;
        if (myCnt > 0) {
            ra = *(const int4*)(sorted + s0);
            rb = *(const int4*)(sorted + s0 + 2);
        }
        int rx[4] = {ra.x, ra.z, rb.x, rb.z};
        int ry[4] = {ra.y, ra.w, rb.y, rb.w};
        #pragma unroll
        for (int j = 0; j < 4; j++) {
            bool ok = j < myCnt;
            mk0[j] = ok ? 1.0f : 0.0f;
            int col = ok ? (rx[j] & 0x3FFFF) : 0;
            ev0[j] = ok ? __int_as_float(ry[j]) : 0.0f;
            xc0[j] = *(const float4*)(x + 4 * (size_t)col);
        }
    }

    for (int c = 0; c < myCnt; c += 4) {
        int c1 = c + 4;
        int4 ra = make_int4(0, 0, 0, 0), rb = ra;
        if (c1 < myCnt) {
            ra = *(const int4*)(sorted + s0 + c1);
            rb = *(const int4*)(sorted + s0 + c1 + 2);
        }
        int rx[4] = {ra.x, ra.z, rb.x, rb.z};
        int ry[4] = {ra.y, ra.w, rb.y, rb.w};
        float mk1[4], ev1[4];
        float4 xc1[4];
        #pragma unroll
        for (int j = 0; j < 4; j++) {
            bool ok = (c1 + j) < myCnt;
            mk1[j] = ok ? 1.0f : 0.0f;
            int col = ok ? (rx[j] & 0x3FFFF) : 0;
            ev1[j] = ok ? __int_as_float(ry[j]) : 0.0f;
            xc1[j] = *(const float4*)(x + 4 * (size_t)col);
        }

        // layer-1 column-terms only; fused relu + mask*accumulate
        #pragma unroll
        for (int k2 = 0; k2 < 16; k2++) {
            float2v w4 = W1v[4 * 16 + k2];
            float2v w5 = W1v[5 * 16 + k2];
            float2v w6 = W1v[6 * 16 + k2];
            float2v w7 = W1v[7 * 16 + k2];
            float2v w8 = W1v[8 * 16 + k2];
            #pragma unroll
            for (int j = 0; j < 4; j++) {
                float2v a = arow[k2];
                a = pk_fma(xc0[j].x, w4, a);
                a = pk_fma(xc0[j].y, w5, a);
                a = pk_fma(xc0[j].z, w6, a);
                a = pk_fma(xc0[j].w, w7, a);
                a = pk_fma(ev0[j],   w8, a);
                float2v zero = {0.0f, 0.0f};
                a = __builtin_elementwise_max(a, zero);
                float2v mm = {mk0[j], mk0[j]};
                acc2[k2] = __builtin_elementwise_fma(a, mm, acc2[k2]);
            }
        }

        #pragma unroll
        for (int j = 0; j < 4; j++) {
            mk0[j] = mk1[j]; ev0[j] = ev1[j]; xc0[j] = xc1[j];
        }
    }

    // combine the 2 slices (lanes 2k, 2k+1)
    float* accf = (float*)acc2;
    #pragma unroll
    for (int j = 0; j < 32; j++) accf[j] += __shfl_xor(accf[j], 1, 64);

    float c_val = 0.0f;
    if (valid && slice == 0) {
        // epilogue: agg = S @ W2 + deg*b2  (hoisted layer 2)
        float fdeg = (float)deg;
        float aout[32];
        #pragma unroll
        for (int j = 0; j < 32; j++) aout[j] = fdeg * b2[j];
        for (int k = 0; k < 32; k++) {
            float sk = accf[k];
            #pragma unroll
            for (int j = 0; j < 32; j++) aout[j] = fmaf(sk, W2[k * 32 + j], aout[j]);
        }

        float zc = bc[0];
        zc = fmaf(xr.x, Wc[0], zc);
        zc = fmaf(xr.y, Wc[1], zc);
        zc = fmaf(xr.z, Wc[2], zc);
        zc = fmaf(xr.w, Wc[3], zc);
        #pragma unroll
        for (int j = 0; j < 32; j++) zc = fmaf(aout[j], Wc[4 + j], zc);
        c_val = softplus_f(zc + 1e-10f);

        int g = n / NN;
        int i = n - g * NN;
        out[(size_t)g * OUT_COLS + i] = c_val;   // unnormalized; div rescales

        if (i >= NN - NF) {
            float zm = bmu[0], zs = bsig[0];
            zm = fmaf(xr.x, Wmu[0], zm);   zs = fmaf(xr.x, Wsig[0], zs);
            zm = fmaf(xr.y, Wmu[1], zm);   zs = fmaf(xr.y, Wsig[1], zs);
            zm = fmaf(xr.z, Wmu[2], zm);   zs = fmaf(xr.z, Wsig[2], zs);
            zm = fmaf(xr.w, Wmu[3], zm);   zs = fmaf(xr.w, Wsig[3], zs);
            #pragma unroll
            for (int j = 0; j < 32; j++) {
                zm = fmaf(aout[j], Wmu[4 + j], zm);
                zs = fmaf(aout[j], Wsig[4 + j], zs);
            }
            float alpha = softplus_f(zm + 1e-20f) + 1e-20f;
            float beta  = softplus_f(zs + 1e-20f) + 1e-20f;
            int k = i - (NN - NF);
            out[(size_t)g * OUT_COLS + NN + k] = alpha / (alpha + beta) * high[k];
        }
    }

    __shared__ float wave_sums[4];
    float s = c_val;
    #pragma unroll
    for (int off = 32; off > 0; off >>= 1) s += __shfl_down(s, off, 64);
    int lane = threadIdx.x & 63;
    int wid  = threadIdx.x >> 6;
    if (lane == 0) wave_sums[wid] = s;
    __syncthreads();
    if (threadIdx.x == 0) {
        float tt = wave_sums[0] + wave_sums[1] + wave_sums[2] + wave_sums[3];
        atomicAdd(sum_out, tt);
    }
}

// ---- P4: in-place normalization of inventory columns ----
__global__ __launch_bounds__(256) void div_kernel(
    const float* __restrict__ sum_in, float* __restrict__ out)
{
    int n = blockIdx.x * 256 + threadIdx.x;
    if (n >= N_NODES) return;
    float inv = 1.0f / (*sum_in + 1e-20f);
    int g = n / NN;
    int i = n - g * NN;
    out[(size_t)g * OUT_COLS + i] *= inv;
}

extern "C" void kernel_launch(void* const* d_in, const int* in_sizes, int n_in,
                              void* d_out, int out_size, void* d_ws, size_t ws_size,
                              hipStream_t stream)
{
    const float* x    = (const float*)d_in[0];
    const int*   ei   = (const int*)d_in[1];
    const float* ea   = (const float*)d_in[2];
    const float* high = (const float*)d_in[3];
    const float* W1   = (const float*)d_in[4];
    const float* b1   = (const float*)d_in[5];
    const float* W2   = (const float*)d_in[6];
    const float* b2   = (const float*)d_in[7];
    const float* Wc   = (const float*)d_in[8];
    const float* bc   = (const float*)d_in[9];
    const float* Wmu  = (const float*)d_in[10];
    const float* bmu  = (const float*)d_in[11];
    const float* Wsig = (const float*)d_in[12];
    const float* bsig = (const float*)d_in[13];
    float* out = (float*)d_out;

    char* ws = (char*)d_ws;
    int2*  bpay    = (int2*)ws;                    // 245*17152*8 = 33,617,920 B
    int*   gcursor = (int*)(ws + 33617920);        // 1024 B
    int*   offs    = (int*)(ws + 33618944);        // 1,000,000 B
    int*   counts  = (int*)(ws + 34618944);        // 1,000,000 B
    float* ssum    = (float*)(ws + 35618944);      // 4 B

    hipMemsetAsync(gcursor, 0, 1024, stream);
    hipMemsetAsync(ssum, 0, 4, stream);

    part_kernel<<<NPBLK, 512, 0, stream>>>(ei, ea, gcursor, bpay);
    csr_kernel<<<NBKT, 512, 0, stream>>>(bpay, gcursor, offs, counts);
    gather_kernel<<<(N_NODES * 2 + 255) / 256, 256, 0, stream>>>(
        x, offs, counts, bpay, W1, b1, W2, b2, Wc, bc, Wmu, bmu, Wsig, bsig,
        high, ssum, out);
    div_kernel<<<(N_NODES + 255) / 256, 256, 0, stream>>>(ssum, out);
}

// Round 13
// 244.250 us; speedup vs baseline: 1.0782x; 1.0221x over previous
//
#include <hip/hip_runtime.h>

#define N_NODES 250000
#define N_EDGES 4000000
#define HID 32
#define NN 50
#define NF 3
#define OUT_COLS (NN + NF)   // 53

#define NB 1024                                   // nodes per bucket
#define NBKT ((N_NODES + NB - 1) / NB)            // 245 buckets
#define CHUNK 8192                                // edges per partition block
#define NPBLK ((N_EDGES + CHUNK - 1) / CHUNK)     // 489
#define BCAP_SLOT 17152                           // fixed bucket capacity (mean+6sigma)
#define HNB 512                                   // nodes per csr half-block
#define SCAP 8960                                 // staged records cap per half

typedef float float2v __attribute__((ext_vector_type(2)));

__device__ __forceinline__ float softplus_f(float v) {
    return fmaxf(v, 0.0f) + log1pf(expf(-fabsf(v)));
}

__device__ __forceinline__ float2v pk_fma(float a, float2v b, float2v c) {
    float2v av = {a, a};
    return __builtin_elementwise_fma(av, b, c);
}

// ---- P1: partition edges into fixed-capacity bucket regions ----
// record: w0 = col | (lrow<<18)  (col<2^18, lrow<2^10), w1 = attr bits
// 1024 threads, 2 blocks/CU -> 32 waves/CU.
__global__ __launch_bounds__(1024) void part_kernel(
    const int* __restrict__ ei, const float* __restrict__ ea,
    int* __restrict__ gcursor, int2* __restrict__ bpay)
{
    __shared__ int hist[NBKT];       // 980 B
    __shared__ int excl[NBKT];
    __shared__ int gbase[NBKT];
    __shared__ int asn[NBKT];
    __shared__ int sh[256];          // 1 KB (scan uses 256 threads)
    __shared__ int2 srec[CHUNK];     // 64 KB — records, bucket-major slots
    __shared__ unsigned char bkt[CHUNK]; // 8 KB
    // total ~78.7 KB -> 2 blocks/CU

    int t = threadIdx.x;
    int cbb = blockIdx.x * CHUNK;
    int cnt = N_EDGES - cbb; if (cnt > CHUNK) cnt = CHUNK;

    for (int i = t; i < NBKT; i += 1024) hist[i] = 0;
    __syncthreads();

    // pass 1: coalesced row loads -> registers, count per bucket
    int r[CHUNK / 1024];
    #pragma unroll
    for (int j = 0; j < CHUNK / 1024; j++) {
        int o = j * 1024 + t;
        r[j] = (o < cnt) ? ei[cbb + o] : -1;
        if (o < cnt) atomicAdd(&hist[r[j] >> 10], 1);
    }
    __syncthreads();

    // scan 245 counters (Hillis-Steele, first 256 threads)
    int v = (t < NBKT) ? hist[t] : 0;
    if (t < 256) sh[t] = v;
    __syncthreads();
    #pragma unroll
    for (int off = 1; off < 256; off <<= 1) {
        int a = (t >= off && t < 256) ? sh[t - off] : 0;
        __syncthreads();
        if (t < 256) sh[t] += a;
        __syncthreads();
    }
    if (t < NBKT) {
        int ex = sh[t] - v;
        excl[t] = ex;
        asn[t] = ex;
        int base = 0;
        if (v > 0) base = atomicAdd(&gcursor[t], v);
        gbase[t] = t * BCAP_SLOT + base;
    }
    __syncthreads();

    // pass 2: coalesced col/attr loads; build records into bucket-major LDS slots
    #pragma unroll
    for (int j = 0; j < CHUNK / 1024; j++) {
        int o = j * 1024 + t;
        if (o < cnt) {
            int row = r[j];
            int b = row >> 10;
            int lrow = row & (NB - 1);
            int col  = ei[N_EDGES + cbb + o];   // coalesced
            float at = ea[cbb + o];             // coalesced
            int slot = atomicAdd(&asn[b], 1);
            srec[slot] = make_int2(col | (lrow << 18), __float_as_int(at));
            bkt[slot] = (unsigned char)b;
        }
    }
    __syncthreads();

    // pass 3: emit bucket-contiguous runs (sequential LDS read, coalesced write)
    for (int s = t; s < cnt; s += 1024) {
        int2 rec = srec[s];
        int b = bkt[s];
        int gpos = gbase[b] + (s - excl[b]);
        if (gpos < (b + 1) * BCAP_SLOT)        // overflow clamp (never in practice)
            bpay[gpos] = rec;
    }
}

// ---- P2: per-bucket counting sort, 2 blocks per bucket (half the nodes each)
// Each block reads the full bucket region (coalesced), stages its half in LDS
// (wave-aggregated compaction), sorts, writes scattered within the window. ----
__global__ __launch_bounds__(512) void csr_kernel(
    int2* __restrict__ bpay, const int* __restrict__ gcursor,
    int* __restrict__ offs, int* __restrict__ counts)
{
    __shared__ int2 recs[SCAP];      // 71,680 B — staged records (arrival order)
    __shared__ int hist[HNB];        // 2 KB
    __shared__ int excl[HNB];        // 2 KB
    __shared__ int sh[512];          // 2 KB
    __shared__ int scnt, lowCnt;
    // total ~77.8 KB -> 2 blocks/CU

    int bb = blockIdx.x;
    int b = bb >> 1;                 // bucket
    int h = bb & 1;                  // half: 0 = lrow<512, 1 = lrow>=512
    int t = threadIdx.x;
    int lane = t & 63;
    int beg = b * BCAP_SLOT;
    int cnt = gcursor[b];
    if (cnt > BCAP_SLOT) cnt = BCAP_SLOT;

    if (t == 0) { scnt = 0; lowCnt = 0; }
    for (int i = t; i < HNB; i += 512) hist[i] = 0;
    __syncthreads();

    // read all bucket records; stage those in my half (wave-aggregated)
    for (int s = t; s < cnt; s += 512) {
        int2 rec = bpay[beg + s];
        int lrow = (rec.x >> 18) & (NB - 1);
        int rh = lrow >> 9;
        bool match = (rh == h);

        if (h == 1) {
            unsigned long long lm = __ballot(rh == 0);
            if (lane == 0 && lm) atomicAdd(&lowCnt, __popcll(lm));
        }

        unsigned long long m = __ballot(match);
        int nm = __popcll(m);
        int wbase = 0;
        if (lane == 0 && nm) wbase = atomicAdd(&scnt, nm);
        wbase = __shfl(wbase, 0, 64);
        if (match) {
            int p = wbase + __popcll(m & ((1ull << lane) - 1ull));
            if (p < SCAP) {
                recs[p] = rec;
                atomicAdd(&hist[lrow & (HNB - 1)], 1);
            }
        }
    }
    __syncthreads();

    int base = beg + (h ? lowCnt : 0);

    // exclusive scan of 512 counters
    int hv = hist[t];
    sh[t] = hv;
    __syncthreads();
    #pragma unroll
    for (int off = 1; off < 512; off <<= 1) {
        int a = (t >= off) ? sh[t - off] : 0;
        __syncthreads();
        sh[t] += a;
        __syncthreads();
    }
    excl[t] = sh[t] - hv;
    __syncthreads();

    // per-node offs/counts (one node per thread)
    int n = (b << 10) + (h << 9) + t;
    if (n < N_NODES) {
        offs[n] = base + excl[t];
        counts[n] = hv;
    }
    __syncthreads();   // placement below mutates excl

    // placement: LDS read, scattered global write within the half window
    int sc = scnt; if (sc > SCAP) sc = SCAP;
    for (int s = t; s < sc; s += 512) {
        int2 rec = recs[s];
        int lr9 = (rec.x >> 18) & (HNB - 1);
        int pos = atomicAdd(&excl[lr9], 1);
        bpay[base + pos] = rec;
    }
}

// ---- P3: gather — layer-1 only (W2 hoisted), row-terms hoisted,
//      2 contiguous slices/node, masked 4-edge chunks, SW pipeline ----
__global__ __launch_bounds__(256) void gather_kernel(
    const float* __restrict__ x, const int* __restrict__ offs,
    const int* __restrict__ counts, const int2* __restrict__ sorted,
    const float* __restrict__ W1, const float* __restrict__ b1,
    const float* __restrict__ W2, const float* __restrict__ b2,
    const float* __restrict__ Wc, const float* __restrict__ bc,
    const float* __restrict__ Wmu, const float* __restrict__ bmu,
    const float* __restrict__ Wsig, const float* __restrict__ bsig,
    const float* __restrict__ high,
    float* __restrict__ sum_out, float* __restrict__ out)
{
    int t = blockIdx.x * 256 + threadIdx.x;
    int n = t >> 1;
    int slice = t & 1;
    bool valid = n < N_NODES;
    int nn = valid ? n : 0;

    int beg = offs[nn];
    int deg = valid ? counts[nn] : 0;
    int half = (deg + 1) >> 1;
    int myCnt = slice ? (deg - half) : half;
    int s0 = beg + slice * half;

    float4 xr = *(const float4*)(x + 4 * (size_t)nn);

    const float2v* W1v = (const float2v*)W1;   // [9][16]
    const float2v* b1v = (const float2v*)b1;

    // hoist row-terms: arow = b1 + xr @ W1[0:4]  (edge-invariant)
    float2v arow[16];
    #pragma unroll
    for (int k2 = 0; k2 < 16; k2++) {
        float2v a = b1v[k2];
        a = pk_fma(xr.x, W1v[0 * 16 + k2], a);
        a = pk_fma(xr.y, W1v[1 * 16 + k2], a);
        a = pk_fma(xr.z, W1v[2 * 16 + k2], a);
        a = pk_fma(xr.w, W1v[3 * 16 + k2], a);
        arow[k2] = a;
    }

    // S = sum over edges of relu(in @ W1 + b1)
    float2v acc2[16];
    #pragma unroll
    for (int j2 = 0; j2 < 16; j2++) { float2v z = {0.f, 0.f}; acc2[j2] = z; }

    // --- software pipeline: recs + xc one chunk ahead ---
    float mk0[4], ev0[4];
    float4 xc0[4];
    {
        int4 ra = make_int4(0, 0, 0, 0), rb = ra;
        if (myCnt > 0) {
            ra = *(const int4*)(sorted + s0);
            rb = *(const int4*)(sorted + s0 + 2);
        }
        int rx[4] = {ra.x, ra.z, rb.x, rb.z};
        int ry[4] = {ra.y, ra.w, rb.y, rb.w};
        #pragma unroll
        for (int j = 0; j < 4; j++) {
            bool ok = j < myCnt;
            mk0[j] = ok ? 1.0f : 0.0f;
            int col = ok ? (rx[j] & 0x3FFFF) : 0;
            ev0[j] = ok ? __int_as_float(ry[j]) : 0.0f;
            xc0[j] = *(const float4*)(x + 4 * (size_t)col);
        }
    }

    for (int c = 0; c < myCnt; c += 4) {
        int c1 = c + 4;
        int4 ra = make_int4(0, 0, 0, 0), rb = ra;
        if (c1 < myCnt) {
            ra = *(const int4*)(sorted + s0 + c1);
            rb = *(const int4*)(sorted + s0 + c1 + 2);
        }
        int rx[4] = {ra.x, ra.z, rb.x, rb.z};
        int ry[4] = {ra.y, ra.w, rb.y, rb.w};
        float mk1[4], ev1[4];
        float4 xc1[4];
        #pragma unroll
        for (int j = 0; j < 4; j++) {
            bool ok = (c1 + j) < myCnt;
            mk1[j] = ok ? 1.0f : 0.0f;
            int col = ok ? (rx[j] & 0x3FFFF) : 0;
            ev1[j] = ok ? __int_as_float(ry[j]) : 0.0f;
            xc1[j] = *(const float4*)(x + 4 * (size_t)col);
        }

        // layer-1 column-terms only; fused relu + mask*accumulate
        #pragma unroll
        for (int k2 = 0; k2 < 16; k2++) {
            float2v w4 = W1v[4 * 16 + k2];
            float2v w5 = W1v[5 * 16 + k2];
            float2v w6 = W1v[6 * 16 + k2];
            float2v w7 = W1v[7 * 16 + k2];
            float2v w8 = W1v[8 * 16 + k2];
            #pragma unroll
            for (int j = 0; j < 4; j++) {
                float2v a = arow[k2];
                a = pk_fma(xc0[j].x, w4, a);
                a = pk_fma(xc0[j].y, w5, a);
                a = pk_fma(xc0[j].z, w6, a);
                a = pk_fma(xc0[j].w, w7, a);
                a = pk_fma(ev0[j],   w8, a);
                float2v zero = {0.0f, 0.0f};
                a = __builtin_elementwise_max(a, zero);
                float2v mm = {mk0[j], mk0[j]};
                acc2[k2] = __builtin_elementwise_fma(a, mm, acc2[k2]);
            }
        }

        #pragma unroll
        for (int j = 0; j < 4; j++) {
            mk0[j] = mk1[j]; ev0[j] = ev1[j]; xc0[j] = xc1[j];
        }
    }

    // combine the 2 slices (lanes 2k, 2k+1)
    float* accf = (float*)acc2;
    #pragma unroll
    for (int j = 0; j < 32; j++) accf[j] += __shfl_xor(accf[j], 1, 64);

    float c_val = 0.0f;
    if (valid && slice == 0) {
        // epilogue: agg = S @ W2 + deg*b2  (hoisted layer 2)
        float fdeg = (float)deg;
        float aout[32];
        #pragma unroll
        for (int j = 0; j < 32; j++) aout[j] = fdeg * b2[j];
        for (int k = 0; k < 32; k++) {
            float sk = accf[k];
            #pragma unroll
            for (int j = 0; j < 32; j++) aout[j] = fmaf(sk, W2[k * 32 + j], aout[j]);
        }

        float zc = bc[0];
        zc = fmaf(xr.x, Wc[0], zc);
        zc = fmaf(xr.y, Wc[1], zc);
        zc = fmaf(xr.z, Wc[2], zc);
        zc = fmaf(xr.w, Wc[3], zc);
        #pragma unroll
        for (int j = 0; j < 32; j++) zc = fmaf(aout[j], Wc[4 + j], zc);
        c_val = softplus_f(zc + 1e-10f);

        int g = n / NN;
        int i = n - g * NN;
        out[(size_t)g * OUT_COLS + i] = c_val;   // unnormalized; div rescales

        if (i >= NN - NF) {
            float zm = bmu[0], zs = bsig[0];
            zm = fmaf(xr.x, Wmu[0], zm);   zs = fmaf(xr.x, Wsig[0], zs);
            zm = fmaf(xr.y, Wmu[1], zm);   zs = fmaf(xr.y, Wsig[1], zs);
            zm = fmaf(xr.z, Wmu[2], zm);   zs = fmaf(xr.z, Wsig[2], zs);
            zm = fmaf(xr.w, Wmu[3], zm);   zs = fmaf(xr.w, Wsig[3], zs);
            #pragma unroll
            for (int j = 0; j < 32; j++) {
                zm = fmaf(aout[j], Wmu[4 + j], zm);
                zs = fmaf(aout[j], Wsig[4 + j], zs);
            }
            float alpha = softplus_f(zm + 1e-20f) + 1e-20f;
            float beta  = softplus_f(zs + 1e-20f) + 1e-20f;
            int k = i - (NN - NF);
            out[(size_t)g * OUT_COLS + NN + k] = alpha / (alpha + beta) * high[k];
        }
    }

    __shared__ float wave_sums[4];
    float s = c_val;
    #pragma unroll
    for (int off = 32; off > 0; off >>= 1) s += __shfl_down(s, off, 64);
    int lane = threadIdx.x & 63;
    int wid  = threadIdx.x >> 6;
    if (lane == 0) wave_sums[wid] = s;
    __syncthreads();
    if (threadIdx.x == 0) {
        float tt = wave_sums[0] + wave_sums[1] + wave_sums[2] + wave_sums[3];
        atomicAdd(sum_out, tt);
    }
}

// ---- P4: in-place normalization of inventory columns ----
__global__ __launch_bounds__(256) void div_kernel(
    const float* __restrict__ sum_in, float* __restrict__ out)
{
    int n = blockIdx.x * 256 + threadIdx.x;
    if (n >= N_NODES) return;
    float inv = 1.0f / (*sum_in + 1e-20f);
    int g = n / NN;
    int i = n - g * NN;
    out[(size_t)g * OUT_COLS + i] *= inv;
}

extern "C" void kernel_launch(void* const* d_in, const int* in_sizes, int n_in,
                              void* d_out, int out_size, void* d_ws, size_t ws_size,
                              hipStream_t stream)
{
    const float* x    = (const float*)d_in[0];
    const int*   ei   = (const int*)d_in[1];
    const float* ea   = (const float*)d_in[2];
    const float* high = (const float*)d_in[3];
    const float* W1   = (const float*)d_in[4];
    const float* b1   = (const float*)d_in[5];
    const float* W2   = (const float*)d_in[6];
    const float* b2   = (const float*)d_in[7];
    const float* Wc   = (const float*)d_in[8];
    const float* bc   = (const float*)d_in[9];
    const float* Wmu  = (const float*)d_in[10];
    const float* bmu  = (const float*)d_in[11];
    const float* Wsig = (const float*)d_in[12];
    const float* bsig = (const float*)d_in[13];
    float* out = (float*)d_out;

    char* ws = (char*)d_ws;
    int2*  bpay    = (int2*)ws;                    // 245*17152*8 = 33,617,920 B
    int*   gcursor = (int*)(ws + 33617920);        // 1024 B
    int*   offs    = (int*)(ws + 33618944);        // 1,000,000 B
    int*   counts  = (int*)(ws + 34618944);        // 1,000,000 B
    float* ssum    = (float*)(ws + 35618944);      // 4 B

    hipMemsetAsync(gcursor, 0, 1024, stream);
    hipMemsetAsync(ssum, 0, 4, stream);

    part_kernel<<<NPBLK, 1024, 0, stream>>>(ei, ea, gcursor, bpay);
    csr_kernel<<<NBKT * 2, 512, 0, stream>>>(bpay, gcursor, offs, counts);
    gather_kernel<<<(N_NODES * 2 + 255) / 256, 256, 0, stream>>>(
        x, offs, counts, bpay, W1, b1, W2, b2, Wc, bc, Wmu, bmu, Wsig, bsig,
        high, ssum, out);
    div_kernel<<<(N_NODES + 255) / 256, 256, 0, stream>>>(ssum, out);
}

// Round 14
// 243.734 us; speedup vs baseline: 1.0804x; 1.0021x over previous
//
#include <hip/hip_runtime.h>

#define N_NODES 250000
#define N_EDGES 4000000
#define HID 32
#define NN 50
#define NF 3
#define OUT_COLS (NN + NF)   // 53

#define NB 1024                                   // nodes per bucket
#define NBKT ((N_NODES + NB - 1) / NB)            // 245 buckets
#define CHUNK 8192                                // edges per partition block
#define NPBLK ((N_EDGES + CHUNK - 1) / CHUNK)     // 489
#define BCAP_SLOT 17152                           // fixed bucket capacity (mean+6sigma)
#define RPT ((BCAP_SLOT + 1023) / 1024)           // 17 records per csr thread

typedef float float2v __attribute__((ext_vector_type(2)));

__device__ __forceinline__ float softplus_f(float v) {
    return fmaxf(v, 0.0f) + log1pf(expf(-fabsf(v)));
}

__device__ __forceinline__ float2v pk_fma(float a, float2v b, float2v c) {
    float2v av = {a, a};
    return __builtin_elementwise_fma(av, b, c);
}

// ---- P1: partition edges into fixed-capacity bucket regions ----
// record: w0 = col | (lrow<<18)  (col<2^18, lrow<2^10), w1 = attr bits
__global__ __launch_bounds__(1024) void part_kernel(
    const int* __restrict__ ei, const float* __restrict__ ea,
    int* __restrict__ gcursor, int2* __restrict__ bpay)
{
    __shared__ int hist[NBKT];
    __shared__ int excl[NBKT];
    __shared__ int gbase[NBKT];
    __shared__ int asn[NBKT];
    __shared__ int sh[256];
    __shared__ int2 srec[CHUNK];     // 64 KB — records, bucket-major slots
    __shared__ unsigned char bkt[CHUNK]; // 8 KB

    int t = threadIdx.x;
    int cbb = blockIdx.x * CHUNK;
    int cnt = N_EDGES - cbb; if (cnt > CHUNK) cnt = CHUNK;

    for (int i = t; i < NBKT; i += 1024) hist[i] = 0;
    __syncthreads();

    // pass 1: coalesced row loads -> registers, count per bucket
    int r[CHUNK / 1024];
    #pragma unroll
    for (int j = 0; j < CHUNK / 1024; j++) {
        int o = j * 1024 + t;
        r[j] = (o < cnt) ? ei[cbb + o] : -1;
        if (o < cnt) atomicAdd(&hist[r[j] >> 10], 1);
    }
    __syncthreads();

    // scan 245 counters (Hillis-Steele, first 256 threads)
    int v = (t < NBKT) ? hist[t] : 0;
    if (t < 256) sh[t] = v;
    __syncthreads();
    #pragma unroll
    for (int off = 1; off < 256; off <<= 1) {
        int a = (t >= off && t < 256) ? sh[t - off] : 0;
        __syncthreads();
        if (t < 256) sh[t] += a;
        __syncthreads();
    }
    if (t < NBKT) {
        int ex = sh[t] - v;
        excl[t] = ex;
        asn[t] = ex;
        int base = 0;
        if (v > 0) base = atomicAdd(&gcursor[t], v);
        gbase[t] = t * BCAP_SLOT + base;
    }
    __syncthreads();

    // pass 2: coalesced col/attr loads; build records into bucket-major LDS slots
    #pragma unroll
    for (int j = 0; j < CHUNK / 1024; j++) {
        int o = j * 1024 + t;
        if (o < cnt) {
            int row = r[j];
            int b = row >> 10;
            int lrow = row & (NB - 1);
            int col  = ei[N_EDGES + cbb + o];   // coalesced
            float at = ea[cbb + o];             // coalesced
            int slot = atomicAdd(&asn[b], 1);
            srec[slot] = make_int2(col | (lrow << 18), __float_as_int(at));
            bkt[slot] = (unsigned char)b;
        }
    }
    __syncthreads();

    // pass 3: emit bucket-contiguous runs (sequential LDS read, coalesced write)
    for (int s = t; s < cnt; s += 1024) {
        int2 rec = srec[s];
        int b = bkt[s];
        int gpos = gbase[b] + (s - excl[b]);
        if (gpos < (b + 1) * BCAP_SLOT)        // overflow clamp (never in practice)
            bpay[gpos] = rec;
    }
}

// ---- P2: per-bucket counting sort — records staged in REGISTERS ----
// One block (1024 thr) per bucket. Single coalesced read; LDS only for
// hist/cursor (8 KB); shfl-based scan (2 barriers); scattered write
// confined to the L2-resident 137 KB bucket window.
__global__ __launch_bounds__(1024) void csr_kernel(
    int2* __restrict__ bpay, const int* __restrict__ gcursor,
    int* __restrict__ offs, int* __restrict__ counts)
{
    __shared__ int hist[NB];         // 4 KB
    __shared__ int excl[NB];         // 4 KB (becomes placement cursor)
    __shared__ int wsum[16];

    int b = blockIdx.x;
    int t = threadIdx.x;
    int lane = t & 63, wid = t >> 6;
    int beg = b * BCAP_SLOT;
    int cnt = gcursor[b];
    if (cnt > BCAP_SLOT) cnt = BCAP_SLOT;

    hist[t] = 0;
    __syncthreads();

    // phase A: read ALL records into registers (coalesced) + histogram
    int2 rec[RPT];
    #pragma unroll
    for (int k = 0; k < RPT; k++) {
        int s = t + k * 1024;
        if (s < cnt) {
            rec[k] = bpay[beg + s];
            atomicAdd(&hist[(rec[k].x >> 18) & (NB - 1)], 1);
        }
    }
    __syncthreads();

    // phase B: exclusive scan of 1024 counters via shfl (2 barriers)
    int hv = hist[t];
    int v = hv;
    #pragma unroll
    for (int off = 1; off < 64; off <<= 1) {
        int u = __shfl_up(v, off, 64);
        if (lane >= off) v += u;
    }
    if (lane == 63) wsum[wid] = v;       // wave inclusive totals
    __syncthreads();
    if (wid == 0) {
        int w = (lane < 16) ? wsum[lane] : 0;
        #pragma unroll
        for (int off = 1; off < 16; off <<= 1) {
            int u = __shfl_up(w, off, 64);
            if (lane >= off) w += u;
        }
        if (lane < 16) wsum[lane] = w;   // inclusive across waves
    }
    __syncthreads();
    int wbase = (wid > 0) ? wsum[wid - 1] : 0;
    int myExcl = wbase + (v - hv);       // exclusive start for node t
    excl[t] = myExcl;

    int n = (b << 10) + t;
    if (n < N_NODES) {
        offs[n] = beg + myExcl;
        counts[n] = hv;
    }
    __syncthreads();   // all excl written before placement mutates them

    // phase C: placement from registers, scattered global write (L2 window)
    #pragma unroll
    for (int k = 0; k < RPT; k++) {
        int s = t + k * 1024;
        if (s < cnt) {
            int lrow = (rec[k].x >> 18) & (NB - 1);
            int pos = atomicAdd(&excl[lrow], 1);
            bpay[beg + pos] = rec[k];
        }
    }
}

// ---- P3: gather — layer-1 only (W2 hoisted), row-terms hoisted,
//      2 contiguous slices/node, masked 4-edge chunks, SW pipeline ----
__global__ __launch_bounds__(256) void gather_kernel(
    const float* __restrict__ x, const int* __restrict__ offs,
    const int* __restrict__ counts, const int2* __restrict__ sorted,
    const float* __restrict__ W1, const float* __restrict__ b1,
    const float* __restrict__ W2, const float* __restrict__ b2,
    const float* __restrict__ Wc, const float* __restrict__ bc,
    const float* __restrict__ Wmu, const float* __restrict__ bmu,
    const float* __restrict__ Wsig, const float* __restrict__ bsig,
    const float* __restrict__ high,
    float* __restrict__ sum_out, float* __restrict__ out)
{
    int t = blockIdx.x * 256 + threadIdx.x;
    int n = t >> 1;
    int slice = t & 1;
    bool valid = n < N_NODES;
    int nn = valid ? n : 0;

    int beg = offs[nn];
    int deg = valid ? counts[nn] : 0;
    int half = (deg + 1) >> 1;
    int myCnt = slice ? (deg - half) : half;
    int s0 = beg + slice * half;

    float4 xr = *(const float4*)(x + 4 * (size_t)nn);

    const float2v* W1v = (const float2v*)W1;   // [9][16]
    const float2v* b1v = (const float2v*)b1;

    // hoist row-terms: arow = b1 + xr @ W1[0:4]  (edge-invariant)
    float2v arow[16];
    #pragma unroll
    for (int k2 = 0; k2 < 16; k2++) {
        float2v a = b1v[k2];
        a = pk_fma(xr.x, W1v[0 * 16 + k2], a);
        a = pk_fma(xr.y, W1v[1 * 16 + k2], a);
        a = pk_fma(xr.z, W1v[2 * 16 + k2], a);
        a = pk_fma(xr.w, W1v[3 * 16 + k2], a);
        arow[k2] = a;
    }

    // S = sum over edges of relu(in @ W1 + b1)
    float2v acc2[16];
    #pragma unroll
    for (int j2 = 0; j2 < 16; j2++) { float2v z = {0.f, 0.f}; acc2[j2] = z; }

    // --- software pipeline: recs + xc one chunk ahead ---
    float mk0[4], ev0[4];
    float4 xc0[4];
    {
        int4 ra = make_int4(0, 0, 0, 0), rb = ra;
        if (myCnt > 0) {
            ra = *(const int4*)(sorted + s0);
            rb = *(const int4*)(sorted + s0 + 2);
        }
        int rx[4] = {ra.x, ra.z, rb.x, rb.z};
        int ry[4] = {ra.y, ra.w, rb.y, rb.w};
        #pragma unroll
        for (int j = 0; j < 4; j++) {
            bool ok = j < myCnt;
            mk0[j] = ok ? 1.0f : 0.0f;
            int col = ok ? (rx[j] & 0x3FFFF) : 0;
            ev0[j] = ok ? __int_as_float(ry[j]) : 0.0f;
            xc0[j] = *(const float4*)(x + 4 * (size_t)col);
        }
    }

    for (int c = 0; c < myCnt; c += 4) {
        int c1 = c + 4;
        int4 ra = make_int4(0, 0, 0, 0), rb = ra;
        if (c1 < myCnt) {
            ra = *(const int4*)(sorted + s0 + c1);
            rb = *(const int4*)(sorted + s0 + c1 + 2);
        }
        int rx[4] = {ra.x, ra.z, rb.x, rb.z};
        int ry[4] = {ra.y, ra.w, rb.y, rb.w};
        float mk1[4], ev1[4];
        float4 xc1[4];
        #pragma unroll
        for (int j = 0; j < 4; j++) {
            bool ok = (c1 + j) < myCnt;
            mk1[j] = ok ? 1.0f : 0.0f;
            int col = ok ? (rx[j] & 0x3FFFF) : 0;
            ev1[j] = ok ? __int_as_float(ry[j]) : 0.0f;
            xc1[j] = *(const float4*)(x + 4 * (size_t)col);
        }

        // layer-1 column-terms only; fused relu + mask*accumulate
        #pragma unroll
        for (int k2 = 0; k2 < 16; k2++) {
            float2v w4 = W1v[4 * 16 + k2];
            float2v w5 = W1v[5 * 16 + k2];
            float2v w6 = W1v[6 * 16 + k2];
            float2v w7 = W1v[7 * 16 + k2];
            float2v w8 = W1v[8 * 16 + k2];
            #pragma unroll
            for (int j = 0; j < 4; j++) {
                float2v a = arow[k2];
                a = pk_fma(xc0[j].x, w4, a);
                a = pk_fma(xc0[j].y, w5, a);
                a = pk_fma(xc0[j].z, w6, a);
                a = pk_fma(xc0[j].w, w7, a);
                a = pk_fma(ev0[j],   w8, a);
                float2v zero = {0.0f, 0.0f};
                a = __builtin_elementwise_max(a, zero);
                float2v mm = {mk0[j], mk0[j]};
                acc2[k2] = __builtin_elementwise_fma(a, mm, acc2[k2]);
            }
        }

        #pragma unroll
        for (int j = 0; j < 4; j++) {
            mk0[j] = mk1[j]; ev0[j] = ev1[j]; xc0[j] = xc1[j];
        }
    }

    // combine the 2 slices (lanes 2k, 2k+1)
    float* accf = (float*)acc2;
    #pragma unroll
    for (int j = 0; j < 32; j++) accf[j] += __shfl_xor(accf[j], 1, 64);

    float c_val = 0.0f;
    if (valid && slice == 0) {
        // epilogue: agg = S @ W2 + deg*b2  (hoisted layer 2)
        float fdeg = (float)deg;
        float aout[32];
        #pragma unroll
        for (int j = 0; j < 32; j++) aout[j] = fdeg * b2[j];
        for (int k = 0; k < 32; k++) {
            float sk = accf[k];
            #pragma unroll
            for (int j = 0; j < 32; j++) aout[j] = fmaf(sk, W2[k * 32 + j], aout[j]);
        }

        float zc = bc[0];
        zc = fmaf(xr.x, Wc[0], zc);
        zc = fmaf(xr.y, Wc[1], zc);
        zc = fmaf(xr.z, Wc[2], zc);
        zc = fmaf(xr.w, Wc[3], zc);
        #pragma unroll
        for (int j = 0; j < 32; j++) zc = fmaf(aout[j], Wc[4 + j], zc);
        c_val = softplus_f(zc + 1e-10f);

        int g = n / NN;
        int i = n - g * NN;
        out[(size_t)g * OUT_COLS + i] = c_val;   // unnormalized; div rescales

        if (i >= NN - NF) {
            float zm = bmu[0], zs = bsig[0];
            zm = fmaf(xr.x, Wmu[0], zm);   zs = fmaf(xr.x, Wsig[0], zs);
            zm = fmaf(xr.y, Wmu[1], zm);   zs = fmaf(xr.y, Wsig[1], zs);
            zm = fmaf(xr.z, Wmu[2], zm);   zs = fmaf(xr.z, Wsig[2], zs);
            zm = fmaf(xr.w, Wmu[3], zm);   zs = fmaf(xr.w, Wsig[3], zs);
            #pragma unroll
            for (int j = 0; j < 32; j++) {
                zm = fmaf(aout[j], Wmu[4 + j], zm);
                zs = fmaf(aout[j], Wsig[4 + j], zs);
            }
            float alpha = softplus_f(zm + 1e-20f) + 1e-20f;
            float beta  = softplus_f(zs + 1e-20f) + 1e-20f;
            int k = i - (NN - NF);
            out[(size_t)g * OUT_COLS + NN + k] = alpha / (alpha + beta) * high[k];
        }
    }

    __shared__ float wave_sums[4];
    float s = c_val;
    #pragma unroll
    for (int off = 32; off > 0; off >>= 1) s += __shfl_down(s, off, 64);
    int lane = threadIdx.x & 63;
    int wid  = threadIdx.x >> 6;
    if (lane == 0) wave_sums[wid] = s;
    __syncthreads();
    if (threadIdx.x == 0) {
        float tt = wave_sums[0] + wave_sums[1] + wave_sums[2] + wave_sums[3];
        atomicAdd(sum_out, tt);
    }
}

// ---- P4: in-place normalization of inventory columns ----
__global__ __launch_bounds__(256) void div_kernel(
    const float* __restrict__ sum_in, float* __restrict__ out)
{
    int n = blockIdx.x * 256 + threadIdx.x;
    if (n >= N_NODES) return;
    float inv = 1.0f / (*sum_in + 1e-20f);
    int g = n / NN;
    int i = n - g * NN;
    out[(size_t)g * OUT_COLS + i] *= inv;
}

extern "C" void kernel_launch(void* const* d_in, const int* in_sizes, int n_in,
                              void* d_out, int out_size, void* d_ws, size_t ws_size,
                              hipStream_t stream)
{
    const float* x    = (const float*)d_in[0];
    const int*   ei   = (const int*)d_in[1];
    const float* ea   = (const float*)d_in[2];
    const float* high = (const float*)d_in[3];
    const float* W1   = (const float*)d_in[4];
    const float* b1   = (const float*)d_in[5];
    const float* W2   = (const float*)d_in[6];
    const float* b2   = (const float*)d_in[7];
    const float* Wc   = (const float*)d_in[8];
    const float* bc   = (const float*)d_in[9];
    const float* Wmu  = (const float*)d_in[10];
    const float* bmu  = (const float*)d_in[11];
    const float* Wsig = (const float*)d_in[12];
    const float* bsig = (const float*)d_in[13];
    float* out = (float*)d_out;

    char* ws = (char*)d_ws;
    int2*  bpay    = (int2*)ws;                    // 245*17152*8 = 33,617,920 B
    int*   gcursor = (int*)(ws + 33617920);        // 1024 B
    int*   offs    = (int*)(ws + 33618944);        // 1,000,000 B
    int*   counts  = (int*)(ws + 34618944);        // 1,000,000 B
    float* ssum    = (float*)(ws + 35618944);      // 4 B

    hipMemsetAsync(gcursor, 0, 1024, stream);
    hipMemsetAsync(ssum, 0, 4, stream);

    part_kernel<<<NPBLK, 1024, 0, stream>>>(ei, ea, gcursor, bpay);
    csr_kernel<<<NBKT, 1024, 0, stream>>>(bpay, gcursor, offs, counts);
    gather_kernel<<<(N_NODES * 2 + 255) / 256, 256, 0, stream>>>(
        x, offs, counts, bpay, W1, b1, W2, b2, Wc, bc, Wmu, bmu, Wsig, bsig,
        high, ssum, out);
    div_kernel<<<(N_NODES + 255) / 256, 256, 0, stream>>>(ssum, out);
}